// Round 1
// baseline (409.392 us; speedup 1.0000x reference)
//
#include <hip/hip_runtime.h>
#include <cstdint>
#include <cstddef>

typedef __attribute__((ext_vector_type(8))) short short8;
typedef __attribute__((ext_vector_type(4))) float f32x4;

#define D_FEAT 512
#define D_HID  1024
#define NCOL   2048   // UV columns = 2*D_HID (U | V)

__device__ __forceinline__ unsigned short f2bf(float f) {
    unsigned u = __builtin_bit_cast(unsigned, f);
    u += 0x7FFFu + ((u >> 16) & 1u);   // round-to-nearest-even
    return (unsigned short)(u >> 16);
}
__device__ __forceinline__ float bf2f(unsigned short h) {
    unsigned u = ((unsigned)h) << 16;
    return __builtin_bit_cast(float, u);
}

// ---------- kernel 1: x fp32 -> bf16 ----------
__global__ __launch_bounds__(256) void cast_x_kernel(const float* __restrict__ x,
                                                     unsigned short* __restrict__ xb,
                                                     int n) {
    int i = (blockIdx.x * 256 + threadIdx.x) * 8;
    if (i >= n) return;
    const float4* xp = (const float4*)(x + i);
    float4 a = xp[0], b = xp[1];
    short8 o;
    o[0] = (short)f2bf(a.x); o[1] = (short)f2bf(a.y);
    o[2] = (short)f2bf(a.z); o[3] = (short)f2bf(a.w);
    o[4] = (short)f2bf(b.x); o[5] = (short)f2bf(b.y);
    o[6] = (short)f2bf(b.z); o[7] = (short)f2bf(b.w);
    *(short8*)(xb + i) = o;
}

// ---------- kernel 2: W1 [1024][1024] fp32 -> w1t bf16 [2048][512] (B^T, U|V stacked) ----------
// w1t[n][k] = W1[k][n]          for n in [0,1024)      (U half)
// w1t[1024+n'][k] = W1[512+k][n'] for n' in [0,1024)   (V half)
__global__ __launch_bounds__(256) void transpose_w1_kernel(const float* __restrict__ W1,
                                                           unsigned short* __restrict__ w1t) {
    __shared__ float tile[32][33];
    const int half = blockIdx.z;           // 0: rows 0..511 of W1, 1: rows 512..1023
    const int kb = blockIdx.y * 32;        // k tile base in [0,512)
    const int nb = blockIdx.x * 32;        // n tile base in [0,1024)
    const int tx = threadIdx.x, ty = threadIdx.y;
    #pragma unroll
    for (int i = 0; i < 32; i += 8)
        tile[ty + i][tx] = W1[(size_t)(half * 512 + kb + ty + i) * 1024 + nb + tx];
    __syncthreads();
    #pragma unroll
    for (int i = 0; i < 32; i += 8)
        w1t[(size_t)(half * 1024 + nb + ty + i) * 512 + kb + tx] = f2bf(tile[tx][ty + i]);
}

// ---------- kernel 3: UV = xb @ w1t^T  (M=50000, K=512, N=2048), +b1 on U half, bf16 out ----------
#define BM 128
#define BN 128
#define BK 64

__global__ __launch_bounds__(256, 2) void gemm_uv_kernel(
    const unsigned short* __restrict__ xb,   // [M][512] bf16
    const unsigned short* __restrict__ w1t,  // [2048][512] bf16 (B^T layout)
    const float* __restrict__ b1,            // [1024]
    unsigned short* __restrict__ UV,         // [M][2048] bf16
    int M)
{
    // staging: sA [128][64] + sB [128][64] = 32 KB; epilogue: 4 waves x [64][80] = 40 KB
    __shared__ __align__(16) unsigned short smem[20480];
    unsigned short* sA = smem;
    unsigned short* sB = smem + 8192;

    const int tid  = threadIdx.x;
    const int wave = tid >> 6;
    const int lane = tid & 63;
    const int q    = lane >> 4;       // quad 0..3
    const int l15  = lane & 15;
    const int wm   = (wave >> 1) * 64;  // wave row offset in block tile
    const int wn   = (wave & 1) * 64;   // wave col offset
    const int n0   = blockIdx.x * BN;   // n-blocks fastest: W1T slice stays hot in L2
    const int m0   = blockIdx.y * BM;

    const int ar = lane >> 3;          // row within 8-row slab
    const int ac = (lane & 7) * 8;     // col elems within 64

    f32x4 zero = {0.f, 0.f, 0.f, 0.f};
    f32x4 acc[4][4];
    #pragma unroll
    for (int i = 0; i < 4; ++i)
        #pragma unroll
        for (int j = 0; j < 4; ++j)
            acc[i][j] = zero;

    #pragma unroll 1
    for (int kt = 0; kt < 8; ++kt) {
        const int k0 = kt * BK;
        __syncthreads();
        // stage A: 128 rows x 64 cols bf16, 4 issues/wave, lane l -> base + l*16B
        #pragma unroll
        for (int i = 0; i < 4; ++i) {
            int slot = wave * 4 + i;          // 0..15
            int row  = slot * 8 + ar;         // 0..127
            int m    = m0 + row; if (m >= M) m = M - 1;
            __builtin_amdgcn_global_load_lds(
                (const __attribute__((address_space(1))) void*)(xb + (size_t)m * D_FEAT + k0 + ac),
                (__attribute__((address_space(3))) void*)(sA + slot * 512),
                16, 0, 0);
        }
        // stage B^T: 128 n-rows x 64 k-cols
        #pragma unroll
        for (int i = 0; i < 4; ++i) {
            int slot = wave * 4 + i;
            int row  = slot * 8 + ar;
            __builtin_amdgcn_global_load_lds(
                (const __attribute__((address_space(1))) void*)(w1t + (size_t)(n0 + row) * D_FEAT + k0 + ac),
                (__attribute__((address_space(3))) void*)(sB + slot * 512),
                16, 0, 0);
        }
        __syncthreads();
        #pragma unroll
        for (int ks = 0; ks < BK; ks += 32) {
            short8 a[4], b[4];
            #pragma unroll
            for (int mt = 0; mt < 4; ++mt)
                a[mt] = *(const short8*)(sA + (wm + mt * 16 + l15) * 64 + ks + q * 8);
            #pragma unroll
            for (int nt = 0; nt < 4; ++nt)
                b[nt] = *(const short8*)(sB + (wn + nt * 16 + l15) * 64 + ks + q * 8);
            #pragma unroll
            for (int mt = 0; mt < 4; ++mt)
                #pragma unroll
                for (int nt = 0; nt < 4; ++nt)
                    acc[mt][nt] = __builtin_amdgcn_mfma_f32_16x16x32_bf16(a[mt], b[nt], acc[mt][nt], 0, 0, 0);
        }
    }

    // epilogue: +b1 (U half only), -> bf16, LDS repack to row-major, 16B stores
    float b1v[4];
    #pragma unroll
    for (int nt = 0; nt < 4; ++nt) {
        int n = n0 + wn + nt * 16 + l15;
        b1v[nt] = (n < D_HID) ? b1[n] : 0.f;
    }
    __syncthreads();                       // all waves done reading sA/sB
    unsigned short* ep = smem + wave * 5120;   // wave-private [64][80] (pad 80 vs 64 for bank spread)
    #pragma unroll
    for (int mt = 0; mt < 4; ++mt)
        #pragma unroll
        for (int nt = 0; nt < 4; ++nt)
            #pragma unroll
            for (int r = 0; r < 4; ++r) {
                // C/D layout: row = q*4 + r, col = l15
                float v = acc[mt][nt][r] + b1v[nt];
                ep[(mt * 16 + q * 4 + r) * 80 + nt * 16 + l15] = f2bf(v);
            }
    __syncthreads();
    #pragma unroll
    for (int i = 0; i < 8; ++i) {
        int flat = i * 64 + lane;          // 0..511
        int r  = flat >> 3;                // 0..63
        int c8 = (flat & 7) * 8;           // 0..56
        int m  = m0 + wm + r;
        if (m < M) {
            short8 v = *(const short8*)(ep + r * 80 + c8);
            *(short8*)(UV + (size_t)m * NCOL + n0 + wn + c8) = v;
        }
    }
}

// ---------- kernel 4: per-edge score = relu(U[s]+V[d]) . W2 + b2 ----------
__global__ __launch_bounds__(256) void edge_score_kernel(
    const unsigned short* __restrict__ UV,
    const int* __restrict__ src, const int* __restrict__ dst,
    const float* __restrict__ W2, const float* __restrict__ b2,
    float* __restrict__ out, int E)
{
    const int wave = threadIdx.x >> 6;
    const int lane = threadIdx.x & 63;
    const int e = blockIdx.x * 4 + wave;
    if (e >= E) return;
    const int s = src[e];
    const int d = dst[e];
    const unsigned short* up = UV + (size_t)s * NCOL + lane * 16;            // U half
    const unsigned short* vp = UV + (size_t)d * NCOL + D_HID + lane * 16;    // V half
    short8 u0 = *(const short8*)up;
    short8 u1 = *(const short8*)(up + 8);
    short8 v0 = *(const short8*)vp;
    short8 v1 = *(const short8*)(vp + 8);
    const float4* wp = (const float4*)(W2 + lane * 16);
    float4 wa = wp[0], wb = wp[1], wc = wp[2], wd = wp[3];
    float w[16] = {wa.x, wa.y, wa.z, wa.w, wb.x, wb.y, wb.z, wb.w,
                   wc.x, wc.y, wc.z, wc.w, wd.x, wd.y, wd.z, wd.w};
    float acc = 0.f;
    #pragma unroll
    for (int i = 0; i < 8; ++i) {
        float h = bf2f((unsigned short)u0[i]) + bf2f((unsigned short)v0[i]);
        acc = fmaf(fmaxf(h, 0.f), w[i], acc);
    }
    #pragma unroll
    for (int i = 0; i < 8; ++i) {
        float h = bf2f((unsigned short)u1[i]) + bf2f((unsigned short)v1[i]);
        acc = fmaf(fmaxf(h, 0.f), w[8 + i], acc);
    }
    #pragma unroll
    for (int off = 1; off < 64; off <<= 1)
        acc += __shfl_xor(acc, off);
    if (lane == 0) out[e] = acc + b2[0];
}

extern "C" void kernel_launch(void* const* d_in, const int* in_sizes, int n_in,
                              void* d_out, int out_size, void* d_ws, size_t ws_size,
                              hipStream_t stream) {
    const float* x  = (const float*)d_in[0];
    const int*   src = (const int*)d_in[1];
    const int*   dst = (const int*)d_in[2];
    const float* W1 = (const float*)d_in[3];
    const float* b1 = (const float*)d_in[4];
    const float* W2 = (const float*)d_in[5];
    const float* b2 = (const float*)d_in[6];
    float* out = (float*)d_out;

    const int M = in_sizes[0] / D_FEAT;   // 50000 nodes
    const int E = in_sizes[1];            // 200000 edges

    // workspace layout: UV bf16 [M][2048] | xb bf16 [M][512] | w1t bf16 [2048][512]
    char* ws = (char*)d_ws;
    unsigned short* UV  = (unsigned short*)ws;
    unsigned short* xb  = (unsigned short*)(ws + (size_t)M * NCOL * 2);
    unsigned short* w1t = (unsigned short*)(ws + (size_t)M * NCOL * 2 + (size_t)M * D_FEAT * 2);

    const int nx = M * D_FEAT;
    cast_x_kernel<<<(nx / 8 + 255) / 256, 256, 0, stream>>>(x, xb, nx);
    transpose_w1_kernel<<<dim3(32, 16, 2), dim3(32, 8), 0, stream>>>(W1, w1t);
    gemm_uv_kernel<<<dim3(NCOL / BN, (M + BM - 1) / BM), 256, 0, stream>>>(xb, w1t, b1, UV, M);
    edge_score_kernel<<<(E + 3) / 4, 256, 0, stream>>>(UV, src, dst, W2, b2, out, E);
}